// Round 10
// baseline (800.285 us; speedup 1.0000x reference)
//
#include <hip/hip_runtime.h>
#include <hip/hip_bf16.h>

// 2-layer GCN + mean pool. N=100000, E=1600000, G=128. dims 3 -> 64 -> 128.
//   h1  = relu( (A_hat x) @ W1 + b1 )        -- aggregate 3-dim x, then tiny GEMM
//   out = (mean_g (A_hat h1)) @ W2 + b2      -- aggregate 64-dim h1, pool, tiny GEMM
//
// R9 -> R10: k_gather2 (52us) fetched 79MB HBM: random src across 8 XCDs
// re-fetches the 12.8MB hs1 per-XCD (L2=4MiB each). Replaced with per-src
// formulation: P[g] = sum_s hs1[s] * (sum_{s->d in g} dinv[d]) + self terms.
//   k_split2: multisplit edges into 8 src super-buckets (1.6MB hs1 slice each,
//             fits one XCD L2); 4B records src_local|g<<14|deg<<21.
//   k_pool  : block b -> bucket b&7 (round-robin blockIdx->XCD heuristic);
//             rows stream from XCD-local L2; accumulate into LDS P_local
//             (32KB, fp32 LDS atomics); flush per-block partial (no atomics).
//   k_out   : reduces 256 partials. gather2 + P memset die.
// Layer-1 dst-CSR build (count/bscan/split/sort) unchanged from R9.
//
// DTYPE-ADAPTIVE: k_detect probes raw bits: flags[0]=bf16?, flags[1]=int64?

typedef __hip_bfloat16 bf16;
#define NGRAPH 128
#define NSB 8        // src super-buckets (one per XCD)
#define NCHUNK 32    // pool blocks per bucket
#define NPART 256    // pool grid = NSB*NCHUNK, one partial slice per block
#define TILE_C 16384
#define TILE_S 4096
#define TILE_S2 8192
#define SCAP   12288 // k_sort LDS stage capacity

__device__ __forceinline__ float b2f(bf16 v) { return __bfloat162float(v); }
__device__ __forceinline__ float bfb(unsigned short u) {
    return __uint_as_float((unsigned)u << 16);
}
__device__ __forceinline__ float fld(const void* p, long long i, int isbf) {
    return isbf ? b2f(((const bf16*)p)[i]) : ((const float*)p)[i];
}
__device__ __forceinline__ int ild(const void* p, long long i, int is64) {
    return is64 ? (int)((const long long*)p)[i] : ((const int*)p)[i];
}

// ---- dtype probe --------------------------------------------------------
__global__ void k_detect(const void* x, const void* ei, int* flags) {
    if (threadIdx.x != 0 || blockIdx.x != 0) return;
    const unsigned short* u = (const unsigned short*)x;
    int good = 0;
    for (int k = 0; k < 128; ++k) {
        int e = (u[2 * k] >> 7) & 0xFF;
        if (e >= 90 && e <= 135) ++good;
    }
    flags[0] = (good >= 96) ? 1 : 0;          // bf16 mode
    const int* w = (const int*)ei;
    int zeros = 0;
    for (int k = 0; k < 64; ++k)
        if (w[2 * k + 1] == 0) ++zeros;
    flags[1] = (zeros >= 56) ? 1 : 0;         // int64 mode
}

// ---- bucket histogram of dst>>8 ----------------------------------------
__global__ void k_count(const void* __restrict__ ei, int* __restrict__ cnt,
                        int E, int NB, const int* __restrict__ flags) {
    __shared__ int h[512];
    for (int b = threadIdx.x; b < NB; b += 256) h[b] = 0;
    __syncthreads();
    int is64 = flags[1];
    long long base = (long long)blockIdx.x * TILE_C;
    int lim = (int)min((long long)TILE_C, (long long)E - base);
    for (int k = threadIdx.x; k < lim; k += 256) {
        int d = ild(ei, (long long)E + base + k, is64);
        atomicAdd(&h[d >> 8], 1);
    }
    __syncthreads();
    for (int b = threadIdx.x; b < NB; b += 256)
        if (h[b]) atomicAdd(&cnt[b], h[b]);
}

// ---- bucket offsets: real-edge (bktoff2) and with-self (bktoff) ---------
__global__ void k_bscan(const int* __restrict__ cnt, int* __restrict__ bktoff2,
                        int* __restrict__ bktoff, int* __restrict__ gcur,
                        int N, int NB) {
    if (threadIdx.x != 0 || blockIdx.x != 0) return;
    int a = 0, b = 0;
    for (int i = 0; i < NB; ++i) {
        int nloc = min(256, N - (i << 8));
        bktoff2[i] = a; bktoff[i] = b; gcur[i] = a;
        a += cnt[i]; b += cnt[i] + nloc;
    }
    bktoff2[NB] = a; bktoff[NB] = b;
}

// ---- multisplit by dst bucket (+ src super-bucket histogram) ------------
__global__ void k_split(const void* __restrict__ ei, int2* __restrict__ edges2,
                        int* __restrict__ gcur, int* __restrict__ cnt2,
                        int E, int NB, int RNG, const int* __restrict__ flags) {
    __shared__ int hist[512], scan_[512], gbase[512], lcur[512];
    __shared__ int h2[NSB];
    __shared__ int2 stage[TILE_S];
    int is64 = flags[1];
    long long base = (long long)blockIdx.x * TILE_S;
    int lim = (int)min((long long)TILE_S, (long long)E - base);
    for (int b = threadIdx.x; b < NB; b += 256) hist[b] = 0;
    if (threadIdx.x < NSB) h2[threadIdx.x] = 0;
    __syncthreads();
    for (int k = threadIdx.x; k < lim; k += 256) {
        int d = ild(ei, (long long)E + base + k, is64);
        atomicAdd(&hist[d >> 8], 1);
    }
    __syncthreads();
    if (threadIdx.x == 0) {
        int a = 0;
        for (int i = 0; i < NB; ++i) { scan_[i] = a; a += hist[i]; }
    }
    __syncthreads();
    for (int b = threadIdx.x; b < NB; b += 256) {
        lcur[b] = scan_[b];
        gbase[b] = hist[b] ? atomicAdd(&gcur[b], hist[b]) : 0;
    }
    __syncthreads();
    for (int k = threadIdx.x; k < lim; k += 256) {
        int s = ild(ei, base + k, is64);
        int d = ild(ei, (long long)E + base + k, is64);
        atomicAdd(&h2[s / RNG], 1);
        int p = atomicAdd(&lcur[d >> 8], 1);
        stage[p] = make_int2(d, s);
    }
    __syncthreads();
    for (int t = threadIdx.x; t < lim; t += 256) {
        int2 r = stage[t];
        int b = r.x >> 8;
        edges2[gbase[b] + (t - scan_[b])] = r;
    }
    if (threadIdx.x < NSB && h2[threadIdx.x])
        atomicAdd(&cnt2[threadIdx.x], h2[threadIdx.x]);
}

// ---- per-bucket counting sort -> meta/row_ptr/dinv/ndat -----------------
__global__ void k_sort(const int2* __restrict__ edges2, const void* __restrict__ batch,
                       const int* __restrict__ cnt, const int* __restrict__ bktoff2,
                       const int* __restrict__ bktoff, unsigned* __restrict__ meta,
                       int* __restrict__ row_ptr, float* __restrict__ dinv,
                       unsigned* __restrict__ ndat, const int* __restrict__ cnt2,
                       int* __restrict__ gcur2, int* __restrict__ boff2g,
                       int N, int Etot, const int* __restrict__ flags) {
    __shared__ int hist[256], loff[257], lcur[256];
    __shared__ unsigned gdeg[256];
    __shared__ unsigned stage[SCAP];
    int b = blockIdx.x;
    int node0 = b << 8;
    int nloc = min(256, N - node0);
    int is64 = flags[1];
    for (int i = threadIdx.x; i < nloc; i += 256) hist[i] = 0;
    __syncthreads();
    int rbase = bktoff2[b], rcnt = cnt[b];
    for (int t = threadIdx.x; t < rcnt; t += 256) {
        int2 r = edges2[rbase + t];
        atomicAdd(&hist[r.x - node0], 1);
    }
    __syncthreads();
    if (threadIdx.x == 0) {
        int a = 0;
        for (int i = 0; i < nloc; ++i) { loff[i] = a; a += hist[i] + 1; }
        loff[nloc] = a;
    }
    __syncthreads();
    int mbase = bktoff[b];
    for (int i = threadIdx.x; i < nloc; i += 256) {
        int node = node0 + i;
        int dg = hist[i];
        dinv[node] = rsqrtf((float)(dg + 1));
        row_ptr[node] = mbase + loff[i];
        int g = ild(batch, node, is64);
        unsigned gd = ((unsigned)g << 17) | ((unsigned)min(dg, 255) << 24);
        ndat[node] = ((unsigned)g << 14) | ((unsigned)min(dg, 255) << 21);
        gdeg[i] = gd;
        lcur[i] = loff[i] + 1;                 // slot 0 of each row = self record
        stage[loff[i]] = (unsigned)node | gd;
    }
    __syncthreads();
    for (int t = threadIdx.x; t < rcnt; t += 256) {
        int2 r = edges2[rbase + t];
        int dl = r.x - node0;
        int p = atomicAdd(&lcur[dl], 1);
        if (p < SCAP) stage[p] = (unsigned)r.y | gdeg[dl];
    }
    __syncthreads();
    int total = loff[nloc];
    for (int t = threadIdx.x; t < total; t += 256) meta[mbase + t] = stage[t];
    if (b == 0 && threadIdx.x == 0) {
        row_ptr[N] = Etot;
        int a = 0;
        for (int i = 0; i < NSB; ++i) { gcur2[i] = a; boff2g[i] = a; a += cnt2[i]; }
        boff2g[NSB] = a;
    }
}

// ---- node pass: graph boundaries + xs = dinv*x --------------------------
__global__ void k_node(const void* __restrict__ x, const void* __restrict__ batch,
                       const float* __restrict__ dinv, float4* __restrict__ xs,
                       int* __restrict__ start, int n, const int* __restrict__ flags) {
    int i = blockIdx.x * blockDim.x + threadIdx.x;
    if (i >= n) return;
    int is64 = flags[1], isbf = flags[0];
    int g = ild(batch, i, is64);
    int gp = (i == 0) ? -1 : ild(batch, i - 1, is64);
    for (int q = gp + 1; q <= g; ++q) start[q] = i;
    if (i == n - 1)
        for (int q = g + 1; q <= NGRAPH; ++q) start[q] = n;
    float di = dinv[i];
    xs[i] = make_float4(di * fld(x, 3LL * i, isbf), di * fld(x, 3LL * i + 1, isbf),
                        di * fld(x, 3LL * i + 2, isbf), 0.0f);
}

// ---- layer 1: CSR node-parallel gather (incl. self edge) ----------------
__global__ void k_gather1(const float4* __restrict__ xs, const float* __restrict__ dinv,
                          const int* __restrict__ row_ptr, const unsigned* __restrict__ meta,
                          float4* __restrict__ aggx, int n) {
    int i = blockIdx.x * blockDim.x + threadIdx.x;
    if (i >= n) return;
    float ax = 0.f, ay = 0.f, az = 0.f;
    int p1 = row_ptr[i + 1];
    for (int p = row_ptr[i]; p < p1; ++p) {
        float4 v = xs[meta[p] & 0x1FFFFu];
        ax += v.x; ay += v.y; az += v.z;
    }
    float di = dinv[i];
    aggx[i] = make_float4(di * ax, di * ay, di * az, 0.0f);
}

// hs1[i][j] = dinv[i] * relu( aggx[i] . W1[:,j] + b1[j] )   (stored bf16)
__global__ void k_h1(const float4* __restrict__ aggx, const float* __restrict__ dinv,
                     const void* __restrict__ W1, const void* __restrict__ b1,
                     bf16* __restrict__ hs1, int n, const int* __restrict__ flags) {
    __shared__ float w[256];  // [0..191]=W1 (3x64 row-major), [192..255]=b1
    int isbf = flags[0];
    if (threadIdx.x < 192) w[threadIdx.x] = fld(W1, threadIdx.x, isbf);
    if (threadIdx.x < 64) w[192 + threadIdx.x] = fld(b1, threadIdx.x, isbf);
    __syncthreads();
    long long t = (long long)blockIdx.x * 256 + threadIdx.x;
    int i = (int)(t >> 6), j = (int)(t & 63);
    if (i >= n) return;
    float4 a = aggx[i];
    float di = dinv[i];
    float acc = a.x * w[j] + a.y * w[64 + j] + a.z * w[128 + j] + w[192 + j];
    hs1[(size_t)i * 64 + j] = __float2bfloat16(di * fmaxf(acc, 0.0f));
}

// ---- multisplit edges by src super-bucket; rec = src_local|g<<14|deg<<21 -
__global__ void k_split2(const void* __restrict__ ei, const unsigned* __restrict__ ndat,
                         int* __restrict__ gcur2, unsigned* __restrict__ rec2,
                         int E, int RNG, const int* __restrict__ flags) {
    __shared__ int sc2[NSB + 1], gb2[NSB], lc2[NSB], h2[NSB];
    __shared__ unsigned stage[TILE_S2];
    int is64 = flags[1];
    long long base = (long long)blockIdx.x * TILE_S2;
    int lim = (int)min((long long)TILE_S2, (long long)E - base);
    if (threadIdx.x < NSB) h2[threadIdx.x] = 0;
    __syncthreads();
    for (int k = threadIdx.x; k < lim; k += 256) {
        int s = ild(ei, base + k, is64);
        atomicAdd(&h2[s / RNG], 1);
    }
    __syncthreads();
    if (threadIdx.x == 0) {
        int a = 0;
        for (int i = 0; i < NSB; ++i) { sc2[i] = a; a += h2[i]; }
        sc2[NSB] = a;
    }
    __syncthreads();
    if (threadIdx.x < NSB) {
        lc2[threadIdx.x] = sc2[threadIdx.x];
        gb2[threadIdx.x] = h2[threadIdx.x] ? atomicAdd(&gcur2[threadIdx.x], h2[threadIdx.x]) : 0;
    }
    __syncthreads();
    for (int k = threadIdx.x; k < lim; k += 256) {
        int s = ild(ei, base + k, is64);
        int d = ild(ei, (long long)E + base + k, is64);
        int b = s / RNG;
        int p = atomicAdd(&lc2[b], 1);
        stage[p] = (unsigned)(s - b * RNG) | ndat[d];
    }
    __syncthreads();
    for (int t = threadIdx.x; t < lim; t += 256) {
        int b = 0;
#pragma unroll
        for (int i = 1; i < NSB; ++i) b += (t >= sc2[i]) ? 1 : 0;
        rec2[gb2[b] + (t - sc2[b])] = stage[t];
    }
}

// ---- layer 2 + pool: XCD-local per-src accumulation ---------------------
// block -> bucket blockIdx&7 (round-robin blockIdx->XCD heuristic): each XCD
// streams only its 1.6MB hs1 slice (L2-resident). LDS P_local, fp32 atomics.
__global__ void __launch_bounds__(256) k_pool(
        const ushort2* __restrict__ hs1v, const unsigned* __restrict__ rec2,
        const unsigned* __restrict__ ndat, const int* __restrict__ boff2g,
        float* __restrict__ Ppart, int N, int RNG) {
    __shared__ float Pl[NGRAPH * 64];  // 32 KB
    int b = blockIdx.x & (NSB - 1);
    int chunk = blockIdx.x >> 3;       // 0..NCHUNK-1
    for (int t = threadIdx.x; t < NGRAPH * 64; t += 256) Pl[t] = 0.f;
    __syncthreads();
    int hw = threadIdx.x >> 5;         // half-wave 0..7
    int fl = threadIdx.x & 31;
    int nodeBase = b * RNG;
    // edges of this bucket
    int e0 = boff2g[b], e1 = boff2g[b + 1];
    int per = (e1 - e0 + NCHUNK - 1) / NCHUNK;
    int c0 = e0 + chunk * per;
    int c1 = min(c0 + per, e1);
#define PSTEP(m, h)                                                             \
    {                                                                           \
        int g = (int)((m >> 14) & 0x7Fu);                                       \
        float w = rsqrtf((float)((m >> 21) & 0xFFu) + 1.0f);                    \
        atomicAdd(&Pl[g * 64 + 2 * fl], w * bfb(h.x));                          \
        atomicAdd(&Pl[g * 64 + 2 * fl + 1], w * bfb(h.y));                      \
    }
    int p = c0 + hw;
    for (; p + 24 < c1; p += 32) {
        unsigned m0 = rec2[p], m1 = rec2[p + 8], m2 = rec2[p + 16], m3 = rec2[p + 24];
        ushort2 h0 = hs1v[(size_t)(nodeBase + (m0 & 0x3FFFu)) * 32 + fl];
        ushort2 h1 = hs1v[(size_t)(nodeBase + (m1 & 0x3FFFu)) * 32 + fl];
        ushort2 h2 = hs1v[(size_t)(nodeBase + (m2 & 0x3FFFu)) * 32 + fl];
        ushort2 h3 = hs1v[(size_t)(nodeBase + (m3 & 0x3FFFu)) * 32 + fl];
        PSTEP(m0, h0) PSTEP(m1, h1) PSTEP(m2, h2) PSTEP(m3, h3)
    }
    for (; p < c1; p += 8) {
        unsigned m = rec2[p];
        ushort2 h = hs1v[(size_t)(nodeBase + (m & 0x3FFFu)) * 32 + fl];
        PSTEP(m, h)
    }
    // self terms: P[batch[i]] += dinv[i]*hs1[i], nodes of this bucket
    int nlen = min(RNG, N - nodeBase); if (nlen < 0) nlen = 0;
    int pern = (nlen + NCHUNK - 1) / NCHUNK;
    int n0 = nodeBase + chunk * pern;
    int n1 = min(n0 + pern, nodeBase + nlen);
    for (int n = n0 + hw; n < n1; n += 8) {
        unsigned m = ndat[n];
        ushort2 h = hs1v[(size_t)n * 32 + fl];
        PSTEP(m, h)
    }
#undef PSTEP
    __syncthreads();
    float* dst = Ppart + (size_t)blockIdx.x * (NGRAPH * 64);
    for (int t = threadIdx.x; t < NGRAPH * 64; t += 256) dst[t] = Pl[t];
}

// out[g][j] = (sum_parts P[g]/count_g) . W2[:,j] + b2[j]  (0 if empty graph)
__global__ void k_out(const float* __restrict__ Ppart, const int* __restrict__ start,
                      const void* __restrict__ W2, const void* __restrict__ b2v,
                      void* __restrict__ out, const int* __restrict__ flags) {
    __shared__ float pm[64];
    int g = blockIdx.x, j = threadIdx.x;
    int isbf = flags[0];
    int c = start[g + 1] - start[g];
    if (j < 64) {
        float v = 0.f;
        for (int s = 0; s < NPART; ++s)
            v += Ppart[(size_t)s * (NGRAPH * 64) + g * 64 + j];
        pm[j] = (c > 0) ? v / (float)c : 0.0f;
    }
    __syncthreads();
    float acc = 0.0f;
    if (c > 0) {
        acc = fld(b2v, j, isbf);
        for (int k = 0; k < 64; ++k) acc += pm[k] * fld(W2, k * 128 + j, isbf);
    }
    if (isbf) ((bf16*)out)[g * 128 + j] = __float2bfloat16(acc);
    else      ((float*)out)[g * 128 + j] = acc;
}

extern "C" void kernel_launch(void* const* d_in, const int* in_sizes, int n_in,
                              void* d_out, int out_size, void* d_ws, size_t ws_size,
                              hipStream_t stream) {
    const void* x    = d_in[0];
    const void* ei   = d_in[1];   // edge_index [2,E] flat: src row then dst row
    const void* batch= d_in[2];
    const void* W1   = d_in[3];
    const void* b1   = d_in[4];
    const void* W2   = d_in[5];
    const void* b2   = d_in[6];

    const int N = in_sizes[0] / 3;
    const int E = in_sizes[1] / 2;
    const int Etot = E + N;
    const int NB = (N + 255) / 256;          // dst buckets (391)
    const int RNG = (N + NSB - 1) / NSB;     // src super-bucket width (12500)

    // ---- workspace layout (512B aligned), total ~42 MB ----
    char* ws = (char*)d_ws;
    size_t off = 0;
    auto alloc = [&](size_t bytes) {
        size_t o = off;
        off = (off + bytes + 511) & ~(size_t)511;
        return o;
    };
    int* flags    = (int*)(ws + alloc(64 * 4));
    int* cnt      = (int*)(ws + alloc((size_t)(NB + NSB) * 4));
    int* cnt2     = cnt + NB;
    int* bktoff2  = (int*)(ws + alloc((size_t)(NB + 1) * 4));
    int* bktoff   = (int*)(ws + alloc((size_t)(NB + 1) * 4));
    int* gcur     = (int*)(ws + alloc((size_t)NB * 4));
    int* gcur2    = (int*)(ws + alloc((size_t)NSB * 4));
    int* boff2g   = (int*)(ws + alloc((size_t)(NSB + 1) * 4));
    int* start    = (int*)(ws + alloc((size_t)(NGRAPH + 1) * 4));
    int* row_ptr  = (int*)(ws + alloc((size_t)(N + 1) * 4));
    float* dinv   = (float*)(ws + alloc((size_t)N * 4));
    unsigned* ndat= (unsigned*)(ws + alloc((size_t)N * 4));
    int2* edges2  = (int2*)(ws + alloc((size_t)E * 8));
    unsigned* rec2= (unsigned*)(ws + alloc((size_t)E * 4));
    unsigned* meta= (unsigned*)(ws + alloc((size_t)Etot * 4));
    float4* xs    = (float4*)(ws + alloc((size_t)N * 16));
    float4* aggx  = (float4*)(ws + alloc((size_t)N * 16));
    bf16* hs1     = (bf16*)(ws + alloc((size_t)N * 64 * 2));
    // Ppart aliases edges2 (dead after k_sort): NPART*32KB = 8MB <= E*8
    float* Ppart  = (float*)edges2;
    (void)ws_size;

    (void)hipMemsetAsync(cnt, 0, (size_t)(NB + NSB) * 4, stream);

    const int nb = (N + 255) / 256;                 // 391
    const int cb = (E + TILE_C - 1) / TILE_C;       // 98
    const int sb = (E + TILE_S - 1) / TILE_S;       // 391
    const int s2b = (E + TILE_S2 - 1) / TILE_S2;    // 196
    const int fb = (N * 64 + 255) / 256;            // 25000

    k_detect<<<1, 64, 0, stream>>>(x, ei, flags);
    k_count<<<cb, 256, 0, stream>>>(ei, cnt, E, NB, flags);
    k_bscan<<<1, 64, 0, stream>>>(cnt, bktoff2, bktoff, gcur, N, NB);
    k_split<<<sb, 256, 0, stream>>>(ei, edges2, gcur, cnt2, E, NB, RNG, flags);
    k_sort<<<NB, 256, 0, stream>>>(edges2, batch, cnt, bktoff2, bktoff, meta,
                                   row_ptr, dinv, ndat, cnt2, gcur2, boff2g,
                                   N, Etot, flags);
    k_node<<<nb, 256, 0, stream>>>(x, batch, dinv, xs, start, N, flags);
    k_gather1<<<nb, 256, 0, stream>>>(xs, dinv, row_ptr, meta, aggx, N);
    k_h1<<<fb, 256, 0, stream>>>(aggx, dinv, W1, b1, hs1, N, flags);
    k_split2<<<s2b, 256, 0, stream>>>(ei, ndat, gcur2, rec2, E, RNG, flags);
    k_pool<<<NPART, 256, 0, stream>>>((const ushort2*)hs1, rec2, ndat, boff2g,
                                      Ppart, N, RNG);
    k_out<<<NGRAPH, 128, 0, stream>>>(Ppart, start, W2, b2, d_out, flags);
}

// Round 11
// 227.099 us; speedup vs baseline: 3.5239x; 3.5239x over previous
//
#include <hip/hip_runtime.h>
#include <hip/hip_bf16.h>

// 2-layer GCN + mean pool. N=100000, E=1600000, G=128. dims 3 -> 64 -> 128.
//   h1  = relu( (A_hat x) @ W1 + b1 )        -- aggregate 3-dim x, then tiny GEMM
//   out = (mean_g (A_hat h1)) @ W2 + b2      -- aggregate 64-dim h1, pool, tiny GEMM
//
// R10 -> R11: k_pool REVERTED (LDS-atomic accumulation 10x worse than register
// acc despite 8x less HBM fetch; 1 block/CU occupancy). Back to R9 gather2
// (register acc, g-monotone flush) with 2048 blocks. Structural fixes:
//   * k_bscan: 1-thread serial 391-iter loop (~60us est) -> 512-thread scan.
//   * k_sort: parallel LDS scan; k_node fused in (dinv/xs/start/row_ptr all
//     written here).
//   * k_l1: gather1+h1 fused per dst-bucket; aggx lives in LDS only.
// 8 kernels total (was 11/12).
//
// DTYPE-ADAPTIVE: k_detect probes raw bits: flags[0]=bf16?, flags[1]=int64?

typedef __hip_bfloat16 bf16;
#define NGRAPH 128
#define NSLICE 8
#define TILE_C 16384
#define TILE_S 4096
#define SCAP   12288 // k_sort LDS stage capacity (mean 4096+256, >60 sigma)

__device__ __forceinline__ float b2f(bf16 v) { return __bfloat162float(v); }
__device__ __forceinline__ float bfb(unsigned short u) {
    return __uint_as_float((unsigned)u << 16);
}
__device__ __forceinline__ float fld(const void* p, long long i, int isbf) {
    return isbf ? b2f(((const bf16*)p)[i]) : ((const float*)p)[i];
}
__device__ __forceinline__ int ild(const void* p, long long i, int is64) {
    return is64 ? (int)((const long long*)p)[i] : ((const int*)p)[i];
}

// ---- dtype probe --------------------------------------------------------
__global__ void k_detect(const void* x, const void* ei, int* flags) {
    if (threadIdx.x != 0 || blockIdx.x != 0) return;
    const unsigned short* u = (const unsigned short*)x;
    int good = 0;
    for (int k = 0; k < 128; ++k) {
        int e = (u[2 * k] >> 7) & 0xFF;
        if (e >= 90 && e <= 135) ++good;
    }
    flags[0] = (good >= 96) ? 1 : 0;          // bf16 mode
    const int* w = (const int*)ei;
    int zeros = 0;
    for (int k = 0; k < 64; ++k)
        if (w[2 * k + 1] == 0) ++zeros;
    flags[1] = (zeros >= 56) ? 1 : 0;         // int64 mode
}

// ---- bucket histogram of dst>>8 ----------------------------------------
__global__ void k_count(const void* __restrict__ ei, int* __restrict__ cnt,
                        int E, int NB, const int* __restrict__ flags) {
    __shared__ int h[512];
    for (int b = threadIdx.x; b < NB; b += 256) h[b] = 0;
    __syncthreads();
    int is64 = flags[1];
    long long base = (long long)blockIdx.x * TILE_C;
    int lim = (int)min((long long)TILE_C, (long long)E - base);
    for (int k = threadIdx.x; k < lim; k += 256) {
        int d = ild(ei, (long long)E + base + k, is64);
        atomicAdd(&h[d >> 8], 1);
    }
    __syncthreads();
    for (int b = threadIdx.x; b < NB; b += 256)
        if (h[b]) atomicAdd(&cnt[b], h[b]);
}

// ---- bucket offsets (parallel scan, NB<=512) ----------------------------
// bktoff2 = exclusive scan of cnt (real edges); bktoff = scan of cnt+nloc.
__global__ void k_bscan(const int* __restrict__ cnt, int* __restrict__ bktoff2,
                        int* __restrict__ bktoff, int* __restrict__ gcur,
                        int N, int NB) {
    __shared__ int sa[512], sb[512];
    int i = threadIdx.x;
    int va = (i < NB) ? cnt[i] : 0;
    int nloc = (i < NB) ? min(256, N - (i << 8)) : 0;
    int vb = va + nloc;
    sa[i] = va; sb[i] = vb;
    __syncthreads();
    for (int d = 1; d < 512; d <<= 1) {
        int ta = (i >= d) ? sa[i - d] : 0;
        int tb = (i >= d) ? sb[i - d] : 0;
        __syncthreads();
        sa[i] += ta; sb[i] += tb;
        __syncthreads();
    }
    if (i < NB) {
        bktoff2[i] = sa[i] - va;
        bktoff[i] = sb[i] - vb;
        gcur[i] = sa[i] - va;
    }
    if (i == NB - 1) { bktoff2[NB] = sa[i]; bktoff[NB] = sb[i]; }
}

// ---- multisplit by dst bucket -------------------------------------------
__global__ void k_split(const void* __restrict__ ei, int2* __restrict__ edges2,
                        int* __restrict__ gcur, int E, int NB,
                        const int* __restrict__ flags) {
    __shared__ int hist[512], scan_[512], gbase[512], lcur[512];
    __shared__ int2 stage[TILE_S];
    int is64 = flags[1];
    long long base = (long long)blockIdx.x * TILE_S;
    int lim = (int)min((long long)TILE_S, (long long)E - base);
    for (int b = threadIdx.x; b < NB; b += 256) hist[b] = 0;
    __syncthreads();
    for (int k = threadIdx.x; k < lim; k += 256) {
        int d = ild(ei, (long long)E + base + k, is64);
        atomicAdd(&hist[d >> 8], 1);
    }
    __syncthreads();
    if (threadIdx.x == 0) {
        int a = 0;
        for (int i = 0; i < NB; ++i) { scan_[i] = a; a += hist[i]; }
    }
    __syncthreads();
    for (int b = threadIdx.x; b < NB; b += 256) {
        lcur[b] = scan_[b];
        gbase[b] = hist[b] ? atomicAdd(&gcur[b], hist[b]) : 0;
    }
    __syncthreads();
    for (int k = threadIdx.x; k < lim; k += 256) {
        int s = ild(ei, base + k, is64);
        int d = ild(ei, (long long)E + base + k, is64);
        int p = atomicAdd(&lcur[d >> 8], 1);
        stage[p] = make_int2(d, s);
    }
    __syncthreads();
    for (int t = threadIdx.x; t < lim; t += 256) {
        int2 r = stage[t];
        int b = r.x >> 8;
        edges2[gbase[b] + (t - scan_[b])] = r;
    }
}

// ---- per-bucket counting sort + fused node pass -------------------------
// Writes meta/row_ptr/dinv/xs/start. meta = src | g<<17 | min(deg,255)<<24;
// slot 0 of each row is the self record.
__global__ void k_sort(const int2* __restrict__ edges2, const void* __restrict__ batch,
                       const void* __restrict__ x, const int* __restrict__ cnt,
                       const int* __restrict__ bktoff2, const int* __restrict__ bktoff,
                       unsigned* __restrict__ meta, int* __restrict__ row_ptr,
                       float* __restrict__ dinv, float4* __restrict__ xs,
                       int* __restrict__ start, int N, int Etot,
                       const int* __restrict__ flags) {
    __shared__ int hist[256], loff[257], lcur[256], sc[256];
    __shared__ unsigned gdeg[256];
    __shared__ unsigned stage[SCAP];
    int b = blockIdx.x;
    int node0 = b << 8;
    int nloc = min(256, N - node0);
    int is64 = flags[1], isbf = flags[0];
    int i = threadIdx.x;
    if (i < nloc) hist[i] = 0;
    __syncthreads();
    int rbase = bktoff2[b], rcnt = cnt[b];
    for (int t = i; t < rcnt; t += 256) {
        int2 r = edges2[rbase + t];
        atomicAdd(&hist[r.x - node0], 1);
    }
    __syncthreads();
    // parallel exclusive scan of (hist+1)
    int v = (i < nloc) ? hist[i] + 1 : 0;
    sc[i] = v;
    __syncthreads();
    for (int d = 1; d < 256; d <<= 1) {
        int t = (i >= d) ? sc[i - d] : 0;
        __syncthreads();
        sc[i] += t;
        __syncthreads();
    }
    if (i < nloc) loff[i] = sc[i] - v;
    if (i == nloc - 1) loff[nloc] = sc[i];
    __syncthreads();
    int mbase = bktoff[b];
    if (i < nloc) {
        int node = node0 + i;
        int dg = hist[i];
        float di = rsqrtf((float)(dg + 1));
        dinv[node] = di;
        row_ptr[node] = mbase + loff[i];
        int g = ild(batch, node, is64);
        // graph boundary detection (batch sorted)
        int gp = (node == 0) ? -1 : ild(batch, node - 1, is64);
        for (int q = gp + 1; q <= g; ++q) start[q] = node;
        if (node == N - 1)
            for (int q = g + 1; q <= NGRAPH; ++q) start[q] = N;
        // xs = dinv * x
        xs[node] = make_float4(di * fld(x, 3LL * node, isbf),
                               di * fld(x, 3LL * node + 1, isbf),
                               di * fld(x, 3LL * node + 2, isbf), 0.0f);
        unsigned gd = ((unsigned)g << 17) | ((unsigned)min(dg, 255) << 24);
        gdeg[i] = gd;
        lcur[i] = loff[i] + 1;                 // slot 0 = self record
        stage[loff[i]] = (unsigned)node | gd;
    }
    __syncthreads();
    for (int t = i; t < rcnt; t += 256) {
        int2 r = edges2[rbase + t];
        int dl = r.x - node0;
        int p = atomicAdd(&lcur[dl], 1);
        if (p < SCAP) stage[p] = (unsigned)r.y | gdeg[dl];
    }
    __syncthreads();
    int total = loff[nloc];
    for (int t = i; t < total; t += 256) meta[mbase + t] = stage[t];
    if (b == 0 && i == 0) row_ptr[N] = Etot;
}

// ---- layer 1 fused: CSR gather + tiny GEMM + relu -> hs1 ----------------
// One block per dst bucket. Phase 1: thread i aggregates node node0+i's row
// (aggx in LDS). Phase 2: (i,j) mapping computes hs1 coalesced.
__global__ void k_l1(const float4* __restrict__ xs, const float* __restrict__ dinv,
                     const int* __restrict__ row_ptr, const unsigned* __restrict__ meta,
                     const void* __restrict__ W1, const void* __restrict__ b1,
                     bf16* __restrict__ hs1, int N, const int* __restrict__ flags) {
    __shared__ float w[256];        // [0..191]=W1 (3x64 row-major), [192..255]=b1
    __shared__ float ag[256][4];
    int isbf = flags[0];
    if (threadIdx.x < 192) w[threadIdx.x] = fld(W1, threadIdx.x, isbf);
    if (threadIdx.x < 64) w[192 + threadIdx.x] = fld(b1, threadIdx.x, isbf);
    int node0 = blockIdx.x << 8;
    int nloc = min(256, N - node0);
    int i = threadIdx.x;
    if (i < nloc) {
        int node = node0 + i;
        float ax = 0.f, ay = 0.f, az = 0.f;
        int p1 = row_ptr[node + 1];
        for (int p = row_ptr[node]; p < p1; ++p) {
            float4 vv = xs[meta[p] & 0x1FFFFu];
            ax += vv.x; ay += vv.y; az += vv.z;
        }
        float di = dinv[node];
        ag[i][0] = di * ax; ag[i][1] = di * ay; ag[i][2] = di * az;
        ag[i][3] = di;      // dinv for output scaling
    }
    __syncthreads();
    for (int t = threadIdx.x; t < (nloc << 6); t += 256) {
        int ii = t >> 6, j = t & 63;
        float acc = ag[ii][0] * w[j] + ag[ii][1] * w[64 + j] + ag[ii][2] * w[128 + j]
                  + w[192 + j];
        hs1[(size_t)(node0 + ii) * 64 + j] = __float2bfloat16(ag[ii][3] * fmaxf(acc, 0.0f));
    }
}

// ---- layer 2 + pool: edge-balanced meta stream (register acc) -----------
__global__ void k_gather2(const ushort2* __restrict__ hs1v, const unsigned* __restrict__ meta,
                          float* __restrict__ P, int Etot, int chunk) {
    int wid = (blockIdx.x * blockDim.x + threadIdx.x) >> 6;
    int lane = threadIdx.x & 63;
    int half = lane >> 5, fl = lane & 31;
    long long base = (long long)wid * chunk;
    if (base >= Etot) return;
    long long end = base + chunk;
    if (end > Etot) end = Etot;
    float accx = 0.f, accy = 0.f;
    int gcur = -1;
    float* Pw = P + (size_t)(wid & (NSLICE - 1)) * (NGRAPH * 64);
    long long p = base + half;
#define STEP(m, h)                                                              \
    {                                                                           \
        int g = (int)((m >> 17) & 0x7Fu);                                       \
        float w = rsqrtf((float)((m >> 24) & 0xFFu) + 1.0f);                    \
        if (g != gcur) {                                                        \
            if (gcur >= 0) {                                                    \
                atomicAdd(&Pw[gcur * 64 + 2 * fl], accx);                       \
                atomicAdd(&Pw[gcur * 64 + 2 * fl + 1], accy);                   \
            }                                                                   \
            accx = accy = 0.f;                                                  \
            gcur = g;                                                           \
        }                                                                       \
        accx += w * bfb(h.x);                                                   \
        accy += w * bfb(h.y);                                                   \
    }
    for (; p + 6 < end; p += 8) {
        unsigned m0 = meta[p], m1 = meta[p + 2], m2 = meta[p + 4], m3 = meta[p + 6];
        ushort2 h0 = hs1v[(size_t)(m0 & 0x1FFFFu) * 32 + fl];
        ushort2 h1 = hs1v[(size_t)(m1 & 0x1FFFFu) * 32 + fl];
        ushort2 h2 = hs1v[(size_t)(m2 & 0x1FFFFu) * 32 + fl];
        ushort2 h3 = hs1v[(size_t)(m3 & 0x1FFFFu) * 32 + fl];
        STEP(m0, h0) STEP(m1, h1) STEP(m2, h2) STEP(m3, h3)
    }
    for (; p < end; p += 2) {
        unsigned m = meta[p];
        ushort2 h = hs1v[(size_t)(m & 0x1FFFFu) * 32 + fl];
        STEP(m, h)
    }
    if (gcur >= 0) {
        atomicAdd(&Pw[gcur * 64 + 2 * fl], accx);
        atomicAdd(&Pw[gcur * 64 + 2 * fl + 1], accy);
    }
#undef STEP
}

// out[g][j] = (sum_slices P[g]/count_g) . W2[:,j] + b2[j]  (0 if empty graph)
__global__ void k_out(const float* __restrict__ P, const int* __restrict__ start,
                      const void* __restrict__ W2, const void* __restrict__ b2v,
                      void* __restrict__ out, const int* __restrict__ flags) {
    __shared__ float pm[64];
    int g = blockIdx.x, j = threadIdx.x;
    int isbf = flags[0];
    int c = start[g + 1] - start[g];
    if (j < 64) {
        float v = 0.f;
        for (int s = 0; s < NSLICE; ++s) v += P[(size_t)s * NGRAPH * 64 + g * 64 + j];
        pm[j] = (c > 0) ? v / (float)c : 0.0f;
    }
    __syncthreads();
    float acc = 0.0f;
    if (c > 0) {
        acc = fld(b2v, j, isbf);
        for (int k = 0; k < 64; ++k) acc += pm[k] * fld(W2, k * 128 + j, isbf);
    }
    if (isbf) ((bf16*)out)[g * 128 + j] = __float2bfloat16(acc);
    else      ((float*)out)[g * 128 + j] = acc;
}

extern "C" void kernel_launch(void* const* d_in, const int* in_sizes, int n_in,
                              void* d_out, int out_size, void* d_ws, size_t ws_size,
                              hipStream_t stream) {
    const void* x    = d_in[0];
    const void* ei   = d_in[1];   // edge_index [2,E] flat: src row then dst row
    const void* batch= d_in[2];
    const void* W1   = d_in[3];
    const void* b1   = d_in[4];
    const void* W2   = d_in[5];
    const void* b2   = d_in[6];

    const int N = in_sizes[0] / 3;
    const int E = in_sizes[1] / 2;
    const int Etot = E + N;
    const int NB = (N + 255) / 256;          // dst buckets (391)

    // ---- workspace layout (512B aligned), total ~37 MB ----
    char* ws = (char*)d_ws;
    size_t off = 0;
    auto alloc = [&](size_t bytes) {
        size_t o = off;
        off = (off + bytes + 511) & ~(size_t)511;
        return o;
    };
    int* flags    = (int*)(ws + alloc(64 * 4));
    int* cnt      = (int*)(ws + alloc((size_t)NB * 4));
    int* bktoff2  = (int*)(ws + alloc((size_t)(NB + 1) * 4));
    int* bktoff   = (int*)(ws + alloc((size_t)(NB + 1) * 4));
    int* gcur     = (int*)(ws + alloc((size_t)NB * 4));
    int* start    = (int*)(ws + alloc((size_t)(NGRAPH + 1) * 4));
    int* row_ptr  = (int*)(ws + alloc((size_t)(N + 1) * 4));
    float* dinv   = (float*)(ws + alloc((size_t)N * 4));
    int2* edges2  = (int2*)(ws + alloc((size_t)E * 8));
    unsigned* meta= (unsigned*)(ws + alloc((size_t)Etot * 4));
    float4* xs    = (float4*)(ws + alloc((size_t)N * 16));
    bf16* hs1     = (bf16*)(ws + alloc((size_t)N * 64 * 2));
    float* P      = (float*)(ws + alloc((size_t)NSLICE * NGRAPH * 64 * 4));
    (void)ws_size;

    (void)hipMemsetAsync(cnt, 0, (size_t)NB * 4, stream);
    (void)hipMemsetAsync(P, 0, (size_t)NSLICE * NGRAPH * 64 * 4, stream);

    const int cb = (E + TILE_C - 1) / TILE_C;       // 98
    const int sb = (E + TILE_S - 1) / TILE_S;       // 391

    // gather2: 2048 blocks -> 8192 waves (32/CU), edge-balanced chunks
    const int g2blocks = 2048;
    const int g2waves = g2blocks * 4;
    const int chunk = (Etot + g2waves - 1) / g2waves;

    k_detect<<<1, 64, 0, stream>>>(x, ei, flags);
    k_count<<<cb, 256, 0, stream>>>(ei, cnt, E, NB, flags);
    k_bscan<<<1, 512, 0, stream>>>(cnt, bktoff2, bktoff, gcur, N, NB);
    k_split<<<sb, 256, 0, stream>>>(ei, edges2, gcur, E, NB, flags);
    k_sort<<<NB, 256, 0, stream>>>(edges2, batch, x, cnt, bktoff2, bktoff, meta,
                                   row_ptr, dinv, xs, start, N, Etot, flags);
    k_l1<<<NB, 256, 0, stream>>>(xs, dinv, row_ptr, meta, W1, b1, hs1, N, flags);
    k_gather2<<<g2blocks, 256, 0, stream>>>((const ushort2*)hs1, meta, P, Etot, chunk);
    k_out<<<NGRAPH, 128, 0, stream>>>(P, start, W2, b2, d_out, flags);
}